// Round 4
// baseline (2255.329 us; speedup 1.0000x reference)
//
#include <hip/hip_runtime.h>

#define NB   16
#define NPC  4096
#define MPC  1024
#define KNB  64
#define FIN  64
#define CAP  448   // candidate capacity per centroid (mean ~137, +26 sigma)

typedef unsigned short u16;
typedef unsigned int   u32;
typedef unsigned long long u64;
typedef __attribute__((ext_vector_type(8))) short short8;
typedef __attribute__((ext_vector_type(4))) float f32x4;

__device__ __forceinline__ u16 f2bf(float f) {
  u32 u = __float_as_uint(f);
  u = u + 0x7fffu + ((u >> 16) & 1u);
  return (u16)(u >> 16);
}
__device__ __forceinline__ float bf2f(u16 b) {
  return __uint_as_float(((u32)b) << 16);
}

// One stage of a 64-lane u64-max reduce on the VALU pipe via DPP.
// Both halves use the same dpp ctrl/mask, so (lo,hi) stay paired.
// bound_ctrl=false => invalid/masked lanes keep old; result in lane 63
// after the 6-stage chain shr1,shr2,shr4,shr8,bcast15(0xa),bcast31(0xc).
#define DPP64_MAX(best, ctrl, rmask) do { \
  u32 _lo = (u32)(best), _hi = (u32)((best) >> 32); \
  u32 _olo = (u32)__builtin_amdgcn_update_dpp((int)_lo, (int)_lo, (ctrl), (rmask), 0xf, false); \
  u32 _ohi = (u32)__builtin_amdgcn_update_dpp((int)_hi, (int)_hi, (ctrl), (rmask), 0xf, false); \
  u64 _o = ((u64)_ohi << 32) | _olo; \
  (best) = _o > (best) ? _o : (best); \
} while (0)

// ---------------------------------------------------------------- FPS
// One block (256 thr = 4 waves = 1 wave/SIMD) per cloud. Bit-exact vs
// numpy: no FMA contraction, (x2+y2)+z2 order. argmax first-index
// tie-break: thread tree keeps lower-index side on >= ; packed
// (dist_bits<<32)|~idx u64 max handles cross-lane/cross-wave ties.
// dist >= 0 so u32 compare of float bits == float compare.
__global__ __launch_bounds__(256)
void fps_kernel(const float* __restrict__ pos, int* __restrict__ idx_out,
                float* __restrict__ pos_out, float* __restrict__ batch_out) {
  const int b = blockIdx.x;
  const int t = threadIdx.x;
  const float* P = pos + (size_t)b * NPC * 3;
  __shared__ float sx[NPC], sy[NPC], sz[NPC];
  __shared__ u64 swave[2][4];
  for (int i = t; i < NPC; i += 256) {
    sx[i] = P[3*i+0]; sy[i] = P[3*i+1]; sz[i] = P[3*i+2];
  }
  for (int i = t; i < MPC; i += 256) batch_out[b*MPC + i] = (float)b;
  __syncthreads();
  float px[16], py[16], pz[16], mind[16];
#pragma unroll
  for (int r = 0; r < 16; ++r) {
    int i = t + (r << 8);
    px[r] = sx[i]; py[r] = sy[i]; pz[r] = sz[i];
    mind[r] = __builtin_inff();
  }
  int last = 0;
  if (t == 0) {
    idx_out[b*MPC] = 0;
    pos_out[(size_t)b*MPC*3 + 0] = sx[0];
    pos_out[(size_t)b*MPC*3 + 1] = sy[0];
    pos_out[(size_t)b*MPC*3 + 2] = sz[0];
  }
  for (int m = 1; m < MPC; ++m) {
    float cx = sx[last], cy = sy[last], cz = sz[last];
#pragma unroll
    for (int r = 0; r < 16; ++r) {
      float dx = __fsub_rn(px[r], cx);
      float dy = __fsub_rn(py[r], cy);
      float dz = __fsub_rn(pz[r], cz);
      float d2 = __fadd_rn(__fadd_rn(__fmul_rn(dx,dx), __fmul_rn(dy,dy)), __fmul_rn(dz,dz));
      mind[r] = fminf(mind[r], d2);
    }
    // thread-level tie-aware (value,idx) argmax tree: pair (k, k+s) has
    // idx(k) < idx(k+s); >= keeps k => first-index tie-break.
    float v[16]; u32 ii[16];
#pragma unroll
    for (int r = 0; r < 16; ++r) { v[r] = mind[r]; ii[r] = (u32)(t + (r << 8)); }
#pragma unroll
    for (int s = 8; s >= 1; s >>= 1) {
#pragma unroll
      for (int k = 0; k < s; ++k) {
        bool ge = v[k] >= v[k+s];
        v[k]  = ge ? v[k]  : v[k+s];
        ii[k] = ge ? ii[k] : ii[k+s];
      }
    }
    u64 best = ((u64)__float_as_uint(v[0]) << 32) | (u32)(~ii[0]);
    DPP64_MAX(best, 0x111, 0xf);   // row_shr:1
    DPP64_MAX(best, 0x112, 0xf);   // row_shr:2
    DPP64_MAX(best, 0x114, 0xf);   // row_shr:4
    DPP64_MAX(best, 0x118, 0xf);   // row_shr:8
    DPP64_MAX(best, 0x142, 0xa);   // row_bcast:15
    DPP64_MAX(best, 0x143, 0xc);   // row_bcast:31
    if ((t & 63) == 63) swave[m & 1][t >> 6] = best;
    __syncthreads();   // single barrier per step (parity double-buffer)
    u64 w0 = swave[m & 1][0], w1 = swave[m & 1][1];
    u64 w2 = swave[m & 1][2], w3 = swave[m & 1][3];
    u64 a0 = w0 > w1 ? w0 : w1;
    u64 a1 = w2 > w3 ? w2 : w3;
    u64 w  = a0 > a1 ? a0 : a1;
    last = (int)(~(u32)w);
    if (t == 0) {
      idx_out[b*MPC + m] = last;
      size_t po = ((size_t)b*MPC + m)*3;
      pos_out[po+0] = sx[last]; pos_out[po+1] = sy[last]; pos_out[po+2] = sz[last];
    }
  }
}

// ---------------------------------------------------------------- y = x @ W1[:64]  (f32 accum, bf16 store)
__global__ __launch_bounds__(256)
void y_kernel(const float* __restrict__ x, const float* __restrict__ w1,
              u16* __restrict__ y) {
  __shared__ float xs[64][68];
  __shared__ float ws[64][68];
  const int t = threadIdx.x;
  const size_t row0 = (size_t)blockIdx.x * 64;
#pragma unroll
  for (int k = 0; k < 4; ++k) {
    int l = t + 256*k;               // 0..1023 float4 index
    int r = l >> 4, c4 = l & 15;
    *(float4*)&xs[r][c4*4] = *(const float4*)&x[(row0 + r)*64 + c4*4];
    *(float4*)&ws[r][c4*4] = *(const float4*)&w1[r*64 + c4*4];
  }
  __syncthreads();
  const int r = t >> 2, c0 = (t & 3) << 4;
  float acc[16];
#pragma unroll
  for (int i = 0; i < 16; ++i) acc[i] = 0.f;
  for (int k = 0; k < 64; ++k) {
    float a = xs[r][k];
#pragma unroll
    for (int j = 0; j < 4; ++j) {
      float4 wv = *(const float4*)&ws[k][c0 + 4*j];
      acc[4*j+0] += a * wv.x; acc[4*j+1] += a * wv.y;
      acc[4*j+2] += a * wv.z; acc[4*j+3] += a * wv.w;
    }
  }
  u32 u[8];
#pragma unroll
  for (int i = 0; i < 8; ++i)
    u[i] = (u32)f2bf(acc[2*i]) | ((u32)f2bf(acc[2*i+1]) << 16);
  u16* dst = y + ((row0 + r)*64 + c0);
  ((uint4*)dst)[0] = make_uint4(u[0],u[1],u[2],u[3]);
  ((uint4*)dst)[1] = make_uint4(u[4],u[5],u[6],u[7]);
}

// ---------------------------------------------------------------- W2 -> bf16 transposed [128][64]
__global__ __launch_bounds__(256)
void w2t_kernel(const float* __restrict__ w2, u16* __restrict__ w2t) {
  int t = blockIdx.x*256 + threadIdx.x;
  if (t < 64*128) {
    int k = t >> 7, c = t & 127;
    w2t[c*64 + k] = f2bf(w2[t]);
  }
}

// ---------------------------------------------------------------- radius + top-64 neighbors
// Replicates lax.top_k(-d2,64) stability via key=(d2_bits, idx) ranking.
__global__ __launch_bounds__(256)
void nbr_kernel(const float* __restrict__ pos, const int* __restrict__ idx,
                int* __restrict__ nbr, int* __restrict__ nvalid) {
  const int bid = blockIdx.x;
  const int sw = (bid & 7) * 512 + (bid >> 3);   // bijective XCD swizzle (4096 = 8*512)
  const int cloud = sw >> 8;
  const int mbase = (sw & 255) << 2;
  __shared__ float sx[NPC], sy[NPC], sz[NPC];
  __shared__ u64 cand[4][CAP];
  const float* P = pos + (size_t)cloud * NPC * 3;
  const int t = threadIdx.x;
  for (int i = t; i < NPC; i += 256) { sx[i]=P[3*i]; sy[i]=P[3*i+1]; sz[i]=P[3*i+2]; }
  __syncthreads();
  const int wv = t >> 6, lane = t & 63;
  const int m = mbase + wv;
  const int g = cloud * MPC + m;
  const int ci = idx[g];
  const float cx = sx[ci], cy = sy[ci], cz = sz[ci];
  const float R2 = 0.04000000059604644775f;      // (float)(0.2*0.2)
  const u64 ltmask = (lane == 0) ? 0ull : (~0ull >> (64 - lane));
  int base = 0;
  for (int i = 0; i < NPC/64; ++i) {
    int j = (i << 6) + lane;
    float dx = __fsub_rn(cx, sx[j]);
    float dy = __fsub_rn(cy, sy[j]);
    float dz = __fsub_rn(cz, sz[j]);
    float d2 = __fadd_rn(__fadd_rn(__fmul_rn(dx,dx), __fmul_rn(dy,dy)), __fmul_rn(dz,dz));
    bool in = d2 <= R2;
    u64 mk = __ballot(in);
    if (in) {
      int slot = base + (int)__popcll(mk & ltmask);
      if (slot < CAP)
        cand[wv][slot] = ((u64)__float_as_uint(d2) << 32) | (u32)j;
    }
    base += (int)__popcll(mk);
  }
  int cnt = base < CAP ? base : CAP;
  u64 mykey[7];
  int myrank[7];
#pragma unroll
  for (int u = 0; u < 7; ++u) {
    int s = lane + (u << 6);
    mykey[u] = (s < cnt) ? cand[wv][s] : ~0ull;
    myrank[u] = 0;
  }
  for (int jj = 0; jj < cnt; ++jj) {
    u64 kj = cand[wv][jj];
#pragma unroll
    for (int u = 0; u < 7; ++u) myrank[u] += (kj < mykey[u]) ? 1 : 0;
  }
#pragma unroll
  for (int u = 0; u < 7; ++u) {
    int s = lane + (u << 6);
    if (s < cnt && myrank[u] < KNB)
      nbr[(size_t)g*KNB + myrank[u]] = cloud*NPC + (int)(mykey[u] & 0xffffffffull);
  }
  if (lane == 0) nvalid[g] = cnt < KNB ? cnt : KNB;
}

// ---------------------------------------------------------------- PointNetConv
// 4 centroids per block (amortizes W2^T staging + barriers 4x); one wave
// per centroid: A = YH[w] (64x64 bf16), B = WT (64x128), acc[4][8].
__global__ __launch_bounds__(256)
void conv_kernel(const float* __restrict__ pos, const int* __restrict__ idx,
                 const int* __restrict__ nbr, const int* __restrict__ nvalid,
                 const u16* __restrict__ y, const u16* __restrict__ w2t,
                 const float* __restrict__ w1, const float* __restrict__ b1,
                 const float* __restrict__ b2, float* __restrict__ out) {
  const int bid = blockIdx.x;
  const int swz = (bid & 7) * 512 + (bid >> 3);   // bijective XCD swizzle (4096 = 8*512)
  const int g0 = swz << 2;                        // 4 consecutive centroids (same cloud)
  const int cloud = g0 >> 10;
  __shared__ u16 YH[4][64][72];   // y rows, then relu'd H1 in-place (same-thread RMW)
  __shared__ u16 WT[128][72];     // W2^T bf16
  __shared__ float rel[4][64][3];
  __shared__ int nbs[4][64];
  __shared__ float w1p[192];
  __shared__ float b1s[64];
  const int t = threadIdx.x;
  const int w = t >> 6, lane = t & 63;
  const int nv = nvalid[g0 + w];                  // wave-uniform
  if (t < 192) w1p[t] = w1[64*64 + t];
  else         b1s[t - 192] = b1[t - 192];
  {
    int j = (lane < nv) ? nbr[(size_t)(g0 + w)*KNB + lane] : -1;
    nbs[w][lane] = j;
    int ci = cloud*NPC + idx[g0 + w];
    float cxx = pos[3*ci], cyy = pos[3*ci+1], czz = pos[3*ci+2];
    float r0 = 0.f, r1 = 0.f, r2 = 0.f;
    if (j >= 0) {
      r0 = pos[3*j]   - cxx;
      r1 = pos[3*j+1] - cyy;
      r2 = pos[3*j+2] - czz;
    }
    rel[w][lane][0] = r0; rel[w][lane][1] = r1; rel[w][lane][2] = r2;
  }
  __syncthreads();
  // gather y rows (256 rows total, 4 threads/row x 32B) + stage WT
#pragma unroll
  for (int p = 0; p < 4; ++p) {
    int row = p*64 + (t >> 2);
    int c = row >> 6, rr = row & 63, part = t & 3;
    int j = nbs[c][rr];
    uint4 v0 = make_uint4(0,0,0,0), v1 = make_uint4(0,0,0,0);
    if (j >= 0) {
      const uint4* src = (const uint4*)(y + (size_t)j*64);
      v0 = src[part*2]; v1 = src[part*2 + 1];
    }
    *(uint4*)&YH[c][rr][part*16]     = v0;
    *(uint4*)&YH[c][rr][part*16 + 8] = v1;
  }
#pragma unroll
  for (int k = 0; k < 4; ++k) {
    int l = t + 256*k;             // 1024 uint4 total
    int row = l >> 3, part = l & 7;
    *(uint4*)&WT[row][part*8] = ((const uint4*)w2t)[l];
  }
  __syncthreads();
  // H1 = relu(y_j + rel @ W1[64:67] + b1), bf16 in-place
#pragma unroll
  for (int p = 0; p < 4; ++p) {
    int row = p*64 + (t >> 2);
    int c = row >> 6, rr = row & 63, c0 = (t & 3) << 4;
    float rx = rel[c][rr][0], ry = rel[c][rr][1], rz = rel[c][rr][2];
#pragma unroll
    for (int cc = 0; cc < 16; ++cc) {
      int col = c0 + cc;
      float vv = bf2f(YH[c][rr][col]) + rx*w1p[col] + ry*w1p[64+col] + rz*w1p[128+col] + b1s[col];
      vv = fmaxf(vv, 0.f);
      YH[c][rr][col] = f2bf(vv);
    }
  }
  __syncthreads();
  // MFMA: wave w computes its centroid's 64x128 H2, then masked col-max
  const int arow = lane & 15, agrp = lane >> 4;
  f32x4 acc[4][8];
#pragma unroll
  for (int mt = 0; mt < 4; ++mt)
#pragma unroll
    for (int nt = 0; nt < 8; ++nt) {
      f32x4 z = {0.f, 0.f, 0.f, 0.f};
      acc[mt][nt] = z;
    }
#pragma unroll
  for (int kk = 0; kk < 2; ++kk) {
    short8 a[4], bm[8];
#pragma unroll
    for (int mt = 0; mt < 4; ++mt)
      a[mt] = *(const short8*)&YH[w][mt*16 + arow][kk*32 + agrp*8];
#pragma unroll
    for (int nt = 0; nt < 8; ++nt)
      bm[nt] = *(const short8*)&WT[nt*16 + arow][kk*32 + agrp*8];
#pragma unroll
    for (int mt = 0; mt < 4; ++mt)
#pragma unroll
      for (int nt = 0; nt < 8; ++nt)
        acc[mt][nt] = __builtin_amdgcn_mfma_f32_16x16x32_bf16(a[mt], bm[nt], acc[mt][nt], 0, 0, 0);
  }
  float p[8];
#pragma unroll
  for (int nt = 0; nt < 8; ++nt) p[nt] = -__builtin_inff();
#pragma unroll
  for (int mt = 0; mt < 4; ++mt) {
#pragma unroll
    for (int r = 0; r < 4; ++r) {
      int slot = mt*16 + agrp*4 + r;
      if (slot < nv) {
#pragma unroll
        for (int nt = 0; nt < 8; ++nt)
          p[nt] = fmaxf(p[nt], acc[mt][nt][r]);
      }
    }
  }
#pragma unroll
  for (int nt = 0; nt < 8; ++nt) {
    p[nt] = fmaxf(p[nt], __shfl_xor(p[nt], 16, 64));
    p[nt] = fmaxf(p[nt], __shfl_xor(p[nt], 32, 64));
  }
  if (lane < 16) {
#pragma unroll
    for (int nt = 0; nt < 8; ++nt) {
      int c = nt*16 + lane;
      out[(size_t)(g0 + w)*128 + c] = (nv > 0) ? p[nt] + b2[c] : 0.f;
    }
  }
}

// ---------------------------------------------------------------- launch
extern "C" void kernel_launch(void* const* d_in, const int* in_sizes, int n_in,
                              void* d_out, int out_size, void* d_ws, size_t ws_size,
                              hipStream_t stream) {
  const float* x   = (const float*)d_in[0];
  const float* pos = (const float*)d_in[1];
  // d_in[2] (batch) unused: layout is known (repeat arange(16), 4096 each)
  const float* W1  = (const float*)d_in[3];
  const float* b1  = (const float*)d_in[4];
  const float* W2  = (const float*)d_in[5];
  const float* b2  = (const float*)d_in[6];

  float* out       = (float*)d_out;                    // [16384,128]
  float* pos_out   = out + (size_t)NB*MPC*128;         // [16384,3]
  float* batch_out = pos_out + (size_t)NB*MPC*3;       // [16384] (written as floats)

  char* ws = (char*)d_ws;
  int* idx    = (int*)(ws);                                    // 16384 * 4   = 64 KB
  int* nvalid = (int*)(ws + 65536);                            // 16384 * 4   = 64 KB
  int* nbr    = (int*)(ws + 131072);                           // 16384*64*4  = 4 MB
  u16* w2t    = (u16*)(ws + 131072 + 4194304);                 // 128*64*2    = 16 KB
  u16* y      = (u16*)(ws + 131072 + 4194304 + 16384);         // 65536*64*2  = 8 MB (16B aligned)

  fps_kernel <<<NB,    256,  0, stream>>>(pos, idx, pos_out, batch_out);
  y_kernel   <<<1024,  256,  0, stream>>>(x, W1, y);
  w2t_kernel <<<32,    256,  0, stream>>>(W2, w2t);
  nbr_kernel <<<4096,  256,  0, stream>>>(pos, idx, nbr, nvalid);
  conv_kernel<<<4096,  256,  0, stream>>>(pos, idx, nbr, nvalid, y, w2t, W1, b1, b2, out);
}

// Round 5
// 1086.863 us; speedup vs baseline: 2.0751x; 2.0751x over previous
//
#include <hip/hip_runtime.h>

#define NB   16
#define NPC  4096
#define MPC  1024
#define KNB  64
#define FIN  64
#define CAP  448   // candidate capacity per centroid (mean ~137, +26 sigma)
#define NBKT 16    // FPS buckets (256 pts each)

typedef unsigned short u16;
typedef unsigned int   u32;
typedef unsigned long long u64;
typedef __attribute__((ext_vector_type(8))) short short8;
typedef __attribute__((ext_vector_type(4))) float f32x4;

__device__ __forceinline__ u16 f2bf(float f) {
  u32 u = __float_as_uint(f);
  u = u + 0x7fffu + ((u >> 16) & 1u);
  return (u16)(u >> 16);
}
__device__ __forceinline__ float bf2f(u16 b) {
  return __uint_as_float(((u32)b) << 16);
}

// ---- DPP wave reduces (VALU pipe). Canonical 6-stage chain; result lane 63.
// bound_ctrl=false => masked/invalid lanes keep old; compiler inserts the
// mandatory DPP hazard waits (raw asm version faulted in R2).
#define DPP64_MAX(best, ctrl, rmask) do { \
  u32 _lo = (u32)(best), _hi = (u32)((best) >> 32); \
  u32 _olo = (u32)__builtin_amdgcn_update_dpp((int)_lo, (int)_lo, (ctrl), (rmask), 0xf, false); \
  u32 _ohi = (u32)__builtin_amdgcn_update_dpp((int)_hi, (int)_hi, (ctrl), (rmask), 0xf, false); \
  u64 _o = ((u64)_ohi << 32) | _olo; \
  (best) = _o > (best) ? _o : (best); \
} while (0)

#define DPP64_MAX_ALL(k) do { \
  DPP64_MAX(k, 0x111, 0xf); DPP64_MAX(k, 0x112, 0xf); \
  DPP64_MAX(k, 0x114, 0xf); DPP64_MAX(k, 0x118, 0xf); \
  DPP64_MAX(k, 0x142, 0xa); DPP64_MAX(k, 0x143, 0xc); \
} while (0)

__device__ __forceinline__ u32 wave_max_u32(u32 x) {
  u32 t;
  t = (u32)__builtin_amdgcn_update_dpp((int)x, (int)x, 0x111, 0xf, 0xf, false); x = x > t ? x : t;
  t = (u32)__builtin_amdgcn_update_dpp((int)x, (int)x, 0x112, 0xf, 0xf, false); x = x > t ? x : t;
  t = (u32)__builtin_amdgcn_update_dpp((int)x, (int)x, 0x114, 0xf, 0xf, false); x = x > t ? x : t;
  t = (u32)__builtin_amdgcn_update_dpp((int)x, (int)x, 0x118, 0xf, 0xf, false); x = x > t ? x : t;
  t = (u32)__builtin_amdgcn_update_dpp((int)x, (int)x, 0x142, 0xa, 0xf, false); x = x > t ? x : t;
  t = (u32)__builtin_amdgcn_update_dpp((int)x, (int)x, 0x143, 0xc, 0xf, false); x = x > t ? x : t;
  return x;
}
__device__ __forceinline__ u32 wave_min_u32(u32 x) {
  u32 t;
  t = (u32)__builtin_amdgcn_update_dpp((int)x, (int)x, 0x111, 0xf, 0xf, false); x = x < t ? x : t;
  t = (u32)__builtin_amdgcn_update_dpp((int)x, (int)x, 0x112, 0xf, 0xf, false); x = x < t ? x : t;
  t = (u32)__builtin_amdgcn_update_dpp((int)x, (int)x, 0x114, 0xf, 0xf, false); x = x < t ? x : t;
  t = (u32)__builtin_amdgcn_update_dpp((int)x, (int)x, 0x118, 0xf, 0xf, false); x = x < t ? x : t;
  t = (u32)__builtin_amdgcn_update_dpp((int)x, (int)x, 0x142, 0xa, 0xf, false); x = x < t ? x : t;
  t = (u32)__builtin_amdgcn_update_dpp((int)x, (int)x, 0x143, 0xc, 0xf, false); x = x < t ? x : t;
  return x;
}

// 4x4x4 Morton cell (coords in [0,1))
__device__ __forceinline__ int cell_of(float x, float y, float z) {
  int ix = (int)(x * 4.f); ix = ix < 0 ? 0 : (ix > 3 ? 3 : ix);
  int iy = (int)(y * 4.f); iy = iy < 0 ? 0 : (iy > 3 ? 3 : iy);
  int iz = (int)(z * 4.f); iz = iz < 0 ? 0 : (iz > 3 ? 3 : iz);
  return (ix & 1) | ((iy & 1) << 1) | ((iz & 1) << 2)
       | ((ix >> 1) << 3) | ((iy >> 1) << 4) | ((iz >> 1) << 5);
}

// ---------------------------------------------------------------- FPS
// One block (512 thr = 8 waves = 2 waves/SIMD) per cloud. Exact bucket
// pruning: 16 Morton-sorted buckets of 256 pts; per step a bucket is
// re-reduced only if dist2(c,bbox)*0.999 < bucketmax — skipping is
// provably a no-op on every mind[] (bbox lower-bounds each point's exact
// float distance; margin >> rounding error), so the mind/argmax sequence
// is bit-identical to the dense version. Distance math unchanged:
// __f*_rn, (x2+y2)+z2, fminf. Tie-break exact via (mindbits<<32)|~origidx
// packed u64 max. Bucket state wave-owned => single barrier per step.
__global__ __launch_bounds__(512)
void fps_kernel(const float* __restrict__ pos, int* __restrict__ idx_out,
                float* __restrict__ pos_out, float* __restrict__ batch_out) {
  const int b = blockIdx.x;
  const int t = threadIdx.x;
  const int w = t >> 6, lane = t & 63;
  const float* P = pos + (size_t)b * NPC * 3;
  __shared__ float sx[NPC], sy[NPC], sz[NPC];   // ORIG-indexed
  __shared__ int   slist[NPC];                  // sorted -> orig
  __shared__ int   hist[64], cellbase[64];
  __shared__ float bbox[NBKT][6];               // lo0,hi0,lo1,hi1,lo2,hi2
  __shared__ u64   bst[2][NBKT];                // per-bucket (mindbits<<32)|~oidx
  __shared__ u64   wmax[2][8];                  // per-wave max of its 2 buckets
  for (int i = t; i < NPC; i += 512) {
    sx[i] = P[3*i+0]; sy[i] = P[3*i+1]; sz[i] = P[3*i+2];
  }
  for (int i = t; i < MPC; i += 512) batch_out[b*MPC + i] = (float)b;
  if (t < 64) hist[t] = 0;
  __syncthreads();
  for (int p = t; p < NPC; p += 512)
    atomicAdd(&hist[cell_of(sx[p], sy[p], sz[p])], 1);
  __syncthreads();
  if (t == 0) {
    int run = 0;
    for (int c = 0; c < 64; ++c) { cellbase[c] = run; run += hist[c]; }
  }
  __syncthreads();
  if (t < 64) hist[t] = 0;
  __syncthreads();
  for (int p = t; p < NPC; p += 512) {
    int c = cell_of(sx[p], sy[p], sz[p]);
    int r = cellbase[c] + atomicAdd(&hist[c], 1);
    slist[r] = p;     // intra-cell order nondeterministic: affects only
  }                   // bucket membership => skip pattern, never values
  __syncthreads();
  // per-thread points: wave w owns buckets 2w, 2w+1; 4 pts/lane/bucket
  float px[8], py[8], pz[8], mind[8];
  int oi[8];
#pragma unroll
  for (int q = 0; q < 2; ++q)
#pragma unroll
    for (int j = 0; j < 4; ++j) {
      int r = (q << 2) | j;
      int s = ((w << 1) | q) * 256 + (j << 6) + lane;
      int o = slist[s];
      oi[r] = o; px[r] = sx[o]; py[r] = sy[o]; pz[r] = sz[o];
      mind[r] = __builtin_inff();
    }
  // bbox per owned bucket (from actual member points; exact min/max)
#pragma unroll
  for (int q = 0; q < 2; ++q) {
    int r0 = q << 2;
    float mn0 = fminf(fminf(px[r0], px[r0+1]), fminf(px[r0+2], px[r0+3]));
    float mx0 = fmaxf(fmaxf(px[r0], px[r0+1]), fmaxf(px[r0+2], px[r0+3]));
    float mn1 = fminf(fminf(py[r0], py[r0+1]), fminf(py[r0+2], py[r0+3]));
    float mx1 = fmaxf(fmaxf(py[r0], py[r0+1]), fmaxf(py[r0+2], py[r0+3]));
    float mn2 = fminf(fminf(pz[r0], pz[r0+1]), fminf(pz[r0+2], pz[r0+3]));
    float mx2 = fmaxf(fmaxf(pz[r0], pz[r0+1]), fmaxf(pz[r0+2], pz[r0+3]));
    // coords >= 0 so u32 compare == float compare
    u32 a0 = wave_min_u32(__float_as_uint(mn0));
    u32 a1 = wave_max_u32(__float_as_uint(mx0));
    u32 a2 = wave_min_u32(__float_as_uint(mn1));
    u32 a3 = wave_max_u32(__float_as_uint(mx1));
    u32 a4 = wave_min_u32(__float_as_uint(mn2));
    u32 a5 = wave_max_u32(__float_as_uint(mx2));
    if (lane == 63) {
      int bkt = (w << 1) | q;
      bbox[bkt][0] = __uint_as_float(a0); bbox[bkt][1] = __uint_as_float(a1);
      bbox[bkt][2] = __uint_as_float(a2); bbox[bkt][3] = __uint_as_float(a3);
      bbox[bkt][4] = __uint_as_float(a4); bbox[bkt][5] = __uint_as_float(a5);
      bst[0][bkt] = ((u64)0x7f800000u << 32);   // +inf => first step updates all
    }
  }
  int last = 0;
  if (t == 0) {
    idx_out[b*MPC] = 0;
    pos_out[(size_t)b*MPC*3 + 0] = sx[0];
    pos_out[(size_t)b*MPC*3 + 1] = sy[0];
    pos_out[(size_t)b*MPC*3 + 2] = sz[0];
  }
  __syncthreads();
  for (int m = 1; m < MPC; ++m) {
    const int pr = m & 1, pv = pr ^ 1;
    const float cx = sx[last], cy = sy[last], cz = sz[last];
    u64 mywave = 0;
#pragma unroll
    for (int q = 0; q < 2; ++q) {
      const int bkt = (w << 1) | q;
      u64 old = bst[pv][bkt];
      float bmax = __uint_as_float((u32)(old >> 32));
      float t0 = fmaxf(fmaxf(bbox[bkt][0] - cx, cx - bbox[bkt][1]), 0.f);
      float t1 = fmaxf(fmaxf(bbox[bkt][2] - cy, cy - bbox[bkt][3]), 0.f);
      float t2 = fmaxf(fmaxf(bbox[bkt][4] - cz, cz - bbox[bkt][5]), 0.f);
      float bound = (t0*t0 + t1*t1) + t2*t2;
      u64 nk;
      if (bound * 0.999f >= bmax) {     // wave-uniform branch
        nk = old;                        // provably no mind change in bucket
      } else {
        u64 kk = 0;
#pragma unroll
        for (int j = 0; j < 4; ++j) {
          int r = (q << 2) | j;
          float dx = __fsub_rn(px[r], cx);
          float dy = __fsub_rn(py[r], cy);
          float dz = __fsub_rn(pz[r], cz);
          float d2 = __fadd_rn(__fadd_rn(__fmul_rn(dx,dx), __fmul_rn(dy,dy)), __fmul_rn(dz,dz));
          mind[r] = fminf(mind[r], d2);
          u64 key = ((u64)__float_as_uint(mind[r]) << 32) | (u32)(~(u32)oi[r]);
          kk = key > kk ? key : kk;
        }
        DPP64_MAX_ALL(kk);               // result lane 63
        nk = kk;
      }
      if (lane == 63) {
        bst[pr][bkt] = nk;
        mywave = mywave > nk ? mywave : nk;
      }
    }
    if (lane == 63) wmax[pr][w] = mywave;
    __syncthreads();   // single barrier per step (parity double-buffer)
    u64 W = wmax[pr][0];
#pragma unroll
    for (int qq = 1; qq < 8; ++qq) {
      u64 o = wmax[pr][qq];
      W = o > W ? o : W;
    }
    last = (int)(~(u32)W);
    if (t == 0) {
      idx_out[b*MPC + m] = last;
      size_t po = ((size_t)b*MPC + m)*3;
      pos_out[po+0] = sx[last]; pos_out[po+1] = sy[last]; pos_out[po+2] = sz[last];
    }
  }
}

// ---------------------------------------------------------------- y = x @ W1[:64]  (f32 accum, bf16 store)
__global__ __launch_bounds__(256)
void y_kernel(const float* __restrict__ x, const float* __restrict__ w1,
              u16* __restrict__ y) {
  __shared__ float xs[64][68];
  __shared__ float ws[64][68];
  const int t = threadIdx.x;
  const size_t row0 = (size_t)blockIdx.x * 64;
#pragma unroll
  for (int k = 0; k < 4; ++k) {
    int l = t + 256*k;               // 0..1023 float4 index
    int r = l >> 4, c4 = l & 15;
    *(float4*)&xs[r][c4*4] = *(const float4*)&x[(row0 + r)*64 + c4*4];
    *(float4*)&ws[r][c4*4] = *(const float4*)&w1[r*64 + c4*4];
  }
  __syncthreads();
  const int r = t >> 2, c0 = (t & 3) << 4;
  float acc[16];
#pragma unroll
  for (int i = 0; i < 16; ++i) acc[i] = 0.f;
  for (int k = 0; k < 64; ++k) {
    float a = xs[r][k];
#pragma unroll
    for (int j = 0; j < 4; ++j) {
      float4 wv = *(const float4*)&ws[k][c0 + 4*j];
      acc[4*j+0] += a * wv.x; acc[4*j+1] += a * wv.y;
      acc[4*j+2] += a * wv.z; acc[4*j+3] += a * wv.w;
    }
  }
  u32 u[8];
#pragma unroll
  for (int i = 0; i < 8; ++i)
    u[i] = (u32)f2bf(acc[2*i]) | ((u32)f2bf(acc[2*i+1]) << 16);
  u16* dst = y + ((row0 + r)*64 + c0);
  ((uint4*)dst)[0] = make_uint4(u[0],u[1],u[2],u[3]);
  ((uint4*)dst)[1] = make_uint4(u[4],u[5],u[6],u[7]);
}

// ---------------------------------------------------------------- W2 -> bf16 transposed [128][64]
__global__ __launch_bounds__(256)
void w2t_kernel(const float* __restrict__ w2, u16* __restrict__ w2t) {
  int t = blockIdx.x*256 + threadIdx.x;
  if (t < 64*128) {
    int k = t >> 7, c = t & 127;
    w2t[c*64 + k] = f2bf(w2[t]);
  }
}

// ---------------------------------------------------------------- radius + top-64 neighbors
// Replicates lax.top_k(-d2,64) stability via key=(d2_bits, idx) ranking.
__global__ __launch_bounds__(256)
void nbr_kernel(const float* __restrict__ pos, const int* __restrict__ idx,
                int* __restrict__ nbr, int* __restrict__ nvalid) {
  const int bid = blockIdx.x;
  const int sw = (bid & 7) * 512 + (bid >> 3);   // bijective XCD swizzle (4096 = 8*512)
  const int cloud = sw >> 8;
  const int mbase = (sw & 255) << 2;
  __shared__ float sx[NPC], sy[NPC], sz[NPC];
  __shared__ u64 cand[4][CAP];
  const float* P = pos + (size_t)cloud * NPC * 3;
  const int t = threadIdx.x;
  for (int i = t; i < NPC; i += 256) { sx[i]=P[3*i]; sy[i]=P[3*i+1]; sz[i]=P[3*i+2]; }
  __syncthreads();
  const int wv = t >> 6, lane = t & 63;
  const int m = mbase + wv;
  const int g = cloud * MPC + m;
  const int ci = idx[g];
  const float cx = sx[ci], cy = sy[ci], cz = sz[ci];
  const float R2 = 0.04000000059604644775f;      // (float)(0.2*0.2)
  const u64 ltmask = (lane == 0) ? 0ull : (~0ull >> (64 - lane));
  int base = 0;
  for (int i = 0; i < NPC/64; ++i) {
    int j = (i << 6) + lane;
    float dx = __fsub_rn(cx, sx[j]);
    float dy = __fsub_rn(cy, sy[j]);
    float dz = __fsub_rn(cz, sz[j]);
    float d2 = __fadd_rn(__fadd_rn(__fmul_rn(dx,dx), __fmul_rn(dy,dy)), __fmul_rn(dz,dz));
    bool in = d2 <= R2;
    u64 mk = __ballot(in);
    if (in) {
      int slot = base + (int)__popcll(mk & ltmask);
      if (slot < CAP)
        cand[wv][slot] = ((u64)__float_as_uint(d2) << 32) | (u32)j;
    }
    base += (int)__popcll(mk);
  }
  int cnt = base < CAP ? base : CAP;
  u64 mykey[7];
  int myrank[7];
#pragma unroll
  for (int u = 0; u < 7; ++u) {
    int s = lane + (u << 6);
    mykey[u] = (s < cnt) ? cand[wv][s] : ~0ull;
    myrank[u] = 0;
  }
  for (int jj = 0; jj < cnt; ++jj) {
    u64 kj = cand[wv][jj];
#pragma unroll
    for (int u = 0; u < 7; ++u) myrank[u] += (kj < mykey[u]) ? 1 : 0;
  }
#pragma unroll
  for (int u = 0; u < 7; ++u) {
    int s = lane + (u << 6);
    if (s < cnt && myrank[u] < KNB)
      nbr[(size_t)g*KNB + myrank[u]] = cloud*NPC + (int)(mykey[u] & 0xffffffffull);
  }
  if (lane == 0) nvalid[g] = cnt < KNB ? cnt : KNB;
}

// ---------------------------------------------------------------- PointNetConv (one block per centroid)
__global__ __launch_bounds__(256)
void conv_kernel(const float* __restrict__ pos, const int* __restrict__ idx,
                 const int* __restrict__ nbr, const int* __restrict__ nvalid,
                 const u16* __restrict__ y, const u16* __restrict__ w2t,
                 const float* __restrict__ w1, const float* __restrict__ b1,
                 const float* __restrict__ b2, float* __restrict__ out) {
  const int bid = blockIdx.x;
  const int g = (bid & 7) * 2048 + (bid >> 3);   // bijective XCD swizzle (16384 = 8*2048)
  const int cloud = g >> 10;
  __shared__ u16 YH[64][72];     // y rows, then relu'd H1 in-place (same-thread RMW)
  __shared__ u16 WT[128][72];    // W2^T bf16
  __shared__ float rel[64][3];
  __shared__ int nbs[64];
  __shared__ float w1p[192];
  __shared__ float b1s[64];
  const int t = threadIdx.x;
  const int nv = nvalid[g];
  if (t < 64) nbs[t] = (t < nv) ? nbr[(size_t)g*KNB + t] : -1;
  if (t < 192) w1p[t] = w1[64*64 + t];
  else         b1s[t - 192] = b1[t - 192];
  __syncthreads();
  if (t < 64) {
    int ci = cloud*NPC + idx[g];
    float cxx = pos[3*ci], cyy = pos[3*ci+1], czz = pos[3*ci+2];
    int j = nbs[t];
    float r0 = 0.f, r1 = 0.f, r2 = 0.f;
    if (t < nv && j >= 0) {
      r0 = pos[3*j]   - cxx;
      r1 = pos[3*j+1] - cyy;
      r2 = pos[3*j+2] - czz;
    }
    rel[t][0] = r0; rel[t][1] = r1; rel[t][2] = r2;
  }
  {
    int row = t >> 2, part = t & 3;
    int j = nbs[row];
    uint4 v0 = make_uint4(0,0,0,0), v1 = make_uint4(0,0,0,0);
    if (row < nv && j >= 0) {
      const uint4* src = (const uint4*)(y + (size_t)j*64);
      v0 = src[part*2]; v1 = src[part*2 + 1];
    }
    *(uint4*)&YH[row][part*16]     = v0;
    *(uint4*)&YH[row][part*16 + 8] = v1;
  }
#pragma unroll
  for (int k = 0; k < 4; ++k) {
    int l = t + 256*k;             // 1024 uint4 total
    int row = l >> 3, part = l & 7;
    *(uint4*)&WT[row][part*8] = ((const uint4*)w2t)[l];
  }
  __syncthreads();
  {
    int s = t >> 2, c0 = (t & 3) << 4;
    float rx = rel[s][0], ry = rel[s][1], rz = rel[s][2];
#pragma unroll
    for (int c = 0; c < 16; ++c) {
      int cc = c0 + c;
      float v = bf2f(YH[s][cc]) + rx*w1p[cc] + ry*w1p[64+cc] + rz*w1p[128+cc] + b1s[cc];
      v = fmaxf(v, 0.f);
      YH[s][cc] = f2bf(v);
    }
  }
  __syncthreads();
  const int wv = t >> 6, lane = t & 63;
  const int arow = lane & 15, agrp = lane >> 4;
  const int col0 = wv << 5;
  f32x4 acc[4][2];
#pragma unroll
  for (int mt = 0; mt < 4; ++mt)
#pragma unroll
    for (int nt = 0; nt < 2; ++nt) {
      f32x4 z = {0.f, 0.f, 0.f, 0.f};
      acc[mt][nt] = z;
    }
#pragma unroll
  for (int kk = 0; kk < 2; ++kk) {
    short8 a[4], bm[2];
#pragma unroll
    for (int mt = 0; mt < 4; ++mt)
      a[mt] = *(const short8*)&YH[mt*16 + arow][kk*32 + agrp*8];
#pragma unroll
    for (int nt = 0; nt < 2; ++nt)
      bm[nt] = *(const short8*)&WT[col0 + nt*16 + arow][kk*32 + agrp*8];
#pragma unroll
    for (int mt = 0; mt < 4; ++mt)
#pragma unroll
      for (int nt = 0; nt < 2; ++nt)
        acc[mt][nt] = __builtin_amdgcn_mfma_f32_16x16x32_bf16(a[mt], bm[nt], acc[mt][nt], 0, 0, 0);
  }
  float p0 = -__builtin_inff(), p1 = -__builtin_inff();
#pragma unroll
  for (int mt = 0; mt < 4; ++mt) {
#pragma unroll
    for (int r = 0; r < 4; ++r) {
      int slot = mt*16 + agrp*4 + r;
      if (slot < nv) {
        p0 = fmaxf(p0, acc[mt][0][r]);
        p1 = fmaxf(p1, acc[mt][1][r]);
      }
    }
  }
  p0 = fmaxf(p0, __shfl_xor(p0, 16, 64));
  p0 = fmaxf(p0, __shfl_xor(p0, 32, 64));
  p1 = fmaxf(p1, __shfl_xor(p1, 16, 64));
  p1 = fmaxf(p1, __shfl_xor(p1, 32, 64));
  if (lane < 16) {
    int c = col0 + lane;
    out[(size_t)g*128 + c]      = (nv > 0) ? p0 + b2[c]      : 0.f;
    out[(size_t)g*128 + c + 16] = (nv > 0) ? p1 + b2[c + 16] : 0.f;
  }
}

// ---------------------------------------------------------------- launch
extern "C" void kernel_launch(void* const* d_in, const int* in_sizes, int n_in,
                              void* d_out, int out_size, void* d_ws, size_t ws_size,
                              hipStream_t stream) {
  const float* x   = (const float*)d_in[0];
  const float* pos = (const float*)d_in[1];
  // d_in[2] (batch) unused: layout is known (repeat arange(16), 4096 each)
  const float* W1  = (const float*)d_in[3];
  const float* b1  = (const float*)d_in[4];
  const float* W2  = (const float*)d_in[5];
  const float* b2  = (const float*)d_in[6];

  float* out       = (float*)d_out;                    // [16384,128]
  float* pos_out   = out + (size_t)NB*MPC*128;         // [16384,3]
  float* batch_out = pos_out + (size_t)NB*MPC*3;       // [16384] (written as floats)

  char* ws = (char*)d_ws;
  int* idx    = (int*)(ws);                                    // 16384 * 4   = 64 KB
  int* nvalid = (int*)(ws + 65536);                            // 16384 * 4   = 64 KB
  int* nbr    = (int*)(ws + 131072);                           // 16384*64*4  = 4 MB
  u16* w2t    = (u16*)(ws + 131072 + 4194304);                 // 128*64*2    = 16 KB
  u16* y      = (u16*)(ws + 131072 + 4194304 + 16384);         // 65536*64*2  = 8 MB (16B aligned)

  fps_kernel <<<NB,    512,  0, stream>>>(pos, idx, pos_out, batch_out);
  y_kernel   <<<1024,  256,  0, stream>>>(x, W1, y);
  w2t_kernel <<<32,    256,  0, stream>>>(W2, w2t);
  nbr_kernel <<<4096,  256,  0, stream>>>(pos, idx, nbr, nvalid);
  conv_kernel<<<16384, 256,  0, stream>>>(pos, idx, nbr, nvalid, y, w2t, W1, b1, b2, out);
}

// Round 6
// 1020.602 us; speedup vs baseline: 2.2098x; 1.0649x over previous
//
#include <hip/hip_runtime.h>

#define NB   16
#define NPC  4096
#define MPC  1024
#define KNB  64
#define FIN  64
#define CAP  448   // candidate capacity per centroid (mean ~137, +26 sigma)

typedef unsigned short u16;
typedef unsigned int   u32;
typedef unsigned long long u64;
typedef __attribute__((ext_vector_type(8))) short short8;
typedef __attribute__((ext_vector_type(4))) float f32x4;

__device__ __forceinline__ u16 f2bf(float f) {
  u32 u = __float_as_uint(f);
  u = u + 0x7fffu + ((u >> 16) & 1u);
  return (u16)(u >> 16);
}
__device__ __forceinline__ float bf2f(u16 b) {
  return __uint_as_float(((u32)b) << 16);
}

// ---- DPP wave reduces (VALU pipe). Canonical 6-stage chain; result lane 63.
// bound_ctrl=false => masked/invalid lanes keep old; compiler inserts the
// mandatory DPP hazard waits (raw asm version faulted in R2).
#define DPP64_MAX(best, ctrl, rmask) do { \
  u32 _lo = (u32)(best), _hi = (u32)((best) >> 32); \
  u32 _olo = (u32)__builtin_amdgcn_update_dpp((int)_lo, (int)_lo, (ctrl), (rmask), 0xf, false); \
  u32 _ohi = (u32)__builtin_amdgcn_update_dpp((int)_hi, (int)_hi, (ctrl), (rmask), 0xf, false); \
  u64 _o = ((u64)_ohi << 32) | _olo; \
  (best) = _o > (best) ? _o : (best); \
} while (0)

#define DPP64_MAX_ALL(k) do { \
  DPP64_MAX(k, 0x111, 0xf); DPP64_MAX(k, 0x112, 0xf); \
  DPP64_MAX(k, 0x114, 0xf); DPP64_MAX(k, 0x118, 0xf); \
  DPP64_MAX(k, 0x142, 0xa); DPP64_MAX(k, 0x143, 0xc); \
} while (0)

__device__ __forceinline__ u32 wave_max_u32(u32 x) {
  u32 t;
  t = (u32)__builtin_amdgcn_update_dpp((int)x, (int)x, 0x111, 0xf, 0xf, false); x = x > t ? x : t;
  t = (u32)__builtin_amdgcn_update_dpp((int)x, (int)x, 0x112, 0xf, 0xf, false); x = x > t ? x : t;
  t = (u32)__builtin_amdgcn_update_dpp((int)x, (int)x, 0x114, 0xf, 0xf, false); x = x > t ? x : t;
  t = (u32)__builtin_amdgcn_update_dpp((int)x, (int)x, 0x118, 0xf, 0xf, false); x = x > t ? x : t;
  t = (u32)__builtin_amdgcn_update_dpp((int)x, (int)x, 0x142, 0xa, 0xf, false); x = x > t ? x : t;
  t = (u32)__builtin_amdgcn_update_dpp((int)x, (int)x, 0x143, 0xc, 0xf, false); x = x > t ? x : t;
  return x;
}
__device__ __forceinline__ u32 wave_min_u32(u32 x) {
  u32 t;
  t = (u32)__builtin_amdgcn_update_dpp((int)x, (int)x, 0x111, 0xf, 0xf, false); x = x < t ? x : t;
  t = (u32)__builtin_amdgcn_update_dpp((int)x, (int)x, 0x112, 0xf, 0xf, false); x = x < t ? x : t;
  t = (u32)__builtin_amdgcn_update_dpp((int)x, (int)x, 0x114, 0xf, 0xf, false); x = x < t ? x : t;
  t = (u32)__builtin_amdgcn_update_dpp((int)x, (int)x, 0x118, 0xf, 0xf, false); x = x < t ? x : t;
  t = (u32)__builtin_amdgcn_update_dpp((int)x, (int)x, 0x142, 0xa, 0xf, false); x = x < t ? x : t;
  t = (u32)__builtin_amdgcn_update_dpp((int)x, (int)x, 0x143, 0xc, 0xf, false); x = x < t ? x : t;
  return x;
}

// 4x4x4 Morton cell (coords in [0,1))
__device__ __forceinline__ int cell_of(float x, float y, float z) {
  int ix = (int)(x * 4.f); ix = ix < 0 ? 0 : (ix > 3 ? 3 : ix);
  int iy = (int)(y * 4.f); iy = iy < 0 ? 0 : (iy > 3 ? 3 : iy);
  int iz = (int)(z * 4.f); iz = iz < 0 ? 0 : (iz > 3 ? 3 : iz);
  return (ix & 1) | ((iy & 1) << 1) | ((iz & 1) << 2)
       | ((ix >> 1) << 3) | ((iy >> 1) << 4) | ((iz >> 1) << 5);
}

// ---------------------------------------------------------------- FPS
// One block (512 thr = 8 waves = 2 waves/SIMD) per cloud. Each wave owns
// one Morton-sorted bucket of 512 points (8/lane); ALL bucket state
// (bbox, running max key) lives in registers — the R5 lesson: LDS state
// reads on the per-step critical path cost more than pruning saves.
// Skip test: dist2(c,bbox)*0.999 >= bucket max mind  =>  d2 >= every
// mind in bucket => fminf identity => skipping is bit-exact. Distance
// math unchanged (__f*_rn, (x2+y2)+z2, fminf); argmax tie-break exact
// via packed (mindbits<<32)|~origidx u64 max. Single barrier per step.
__global__ __launch_bounds__(512)
void fps_kernel(const float* __restrict__ pos, int* __restrict__ idx_out,
                float* __restrict__ pos_out, float* __restrict__ batch_out) {
  const int b = blockIdx.x;
  const int t = threadIdx.x;
  const int w = t >> 6, lane = t & 63;
  const float* P = pos + (size_t)b * NPC * 3;
  __shared__ float sx[NPC], sy[NPC], sz[NPC];   // ORIG-indexed
  __shared__ int   slist[NPC];                  // sorted -> orig
  __shared__ int   hist[64], cellbase[64];
  __shared__ u64   wmax[2][8];                  // per-wave max key, parity-dbuf
  for (int i = t; i < NPC; i += 512) {
    sx[i] = P[3*i+0]; sy[i] = P[3*i+1]; sz[i] = P[3*i+2];
  }
  for (int i = t; i < MPC; i += 512) batch_out[b*MPC + i] = (float)b;
  if (t < 64) hist[t] = 0;
  __syncthreads();
  for (int p = t; p < NPC; p += 512)
    atomicAdd(&hist[cell_of(sx[p], sy[p], sz[p])], 1);
  __syncthreads();
  if (t == 0) {
    int run = 0;
    for (int c = 0; c < 64; ++c) { cellbase[c] = run; run += hist[c]; }
  }
  __syncthreads();
  if (t < 64) hist[t] = 0;
  __syncthreads();
  for (int p = t; p < NPC; p += 512) {
    int c = cell_of(sx[p], sy[p], sz[p]);
    int r = cellbase[c] + atomicAdd(&hist[c], 1);
    slist[r] = p;     // intra-cell order nondeterministic: affects only
  }                   // bucket membership => skip pattern, never values
  __syncthreads();
  // wave w owns sorted chunk [512w, 512w+512): 8 pts/lane
  float px[8], py[8], pz[8], mind[8];
  u32 noi[8];
#pragma unroll
  for (int j = 0; j < 8; ++j) {
    int s = (w << 9) + (j << 6) + lane;
    int o = slist[s];
    noi[j] = ~(u32)o;
    px[j] = sx[o]; py[j] = sy[o]; pz[j] = sz[o];
    mind[j] = __builtin_inff();
  }
  // wave bbox -> uniform registers (coords >= 0 so u32 cmp == f32 cmp)
  float mnx = px[0], mxx = px[0], mny = py[0], mxy = py[0], mnz = pz[0], mxz = pz[0];
#pragma unroll
  for (int j = 1; j < 8; ++j) {
    mnx = fminf(mnx, px[j]); mxx = fmaxf(mxx, px[j]);
    mny = fminf(mny, py[j]); mxy = fmaxf(mxy, py[j]);
    mnz = fminf(mnz, pz[j]); mxz = fmaxf(mxz, pz[j]);
  }
  const float blox = __uint_as_float(__builtin_amdgcn_readlane((int)wave_min_u32(__float_as_uint(mnx)), 63));
  const float bhix = __uint_as_float(__builtin_amdgcn_readlane((int)wave_max_u32(__float_as_uint(mxx)), 63));
  const float bloy = __uint_as_float(__builtin_amdgcn_readlane((int)wave_min_u32(__float_as_uint(mny)), 63));
  const float bhiy = __uint_as_float(__builtin_amdgcn_readlane((int)wave_max_u32(__float_as_uint(mxy)), 63));
  const float bloz = __uint_as_float(__builtin_amdgcn_readlane((int)wave_min_u32(__float_as_uint(mnz)), 63));
  const float bhiz = __uint_as_float(__builtin_amdgcn_readlane((int)wave_max_u32(__float_as_uint(mxz)), 63));
  // wave state: running max key (value bits, ~origidx). +inf => step 1 updates.
  u32 wk_hi = 0x7f800000u, wk_lo = 0u;
  int last = 0;
  if (t == 0) {
    idx_out[b*MPC] = 0;
    pos_out[(size_t)b*MPC*3 + 0] = sx[0];
    pos_out[(size_t)b*MPC*3 + 1] = sy[0];
    pos_out[(size_t)b*MPC*3 + 2] = sz[0];
  }
  __syncthreads();
  for (int m = 1; m < MPC; ++m) {
    const int pr = m & 1;
    const float cx = sx[last], cy = sy[last], cz = sz[last];
    float t0 = fmaxf(fmaxf(blox - cx, cx - bhix), 0.f);
    float t1 = fmaxf(fmaxf(bloy - cy, cy - bhiy), 0.f);
    float t2 = fmaxf(fmaxf(bloz - cz, cz - bhiz), 0.f);
    float bound = (t0*t0 + t1*t1) + t2*t2;
    if (bound * 0.999f < __uint_as_float(wk_hi)) {   // wave-uniform branch
      u64 kk = 0;
#pragma unroll
      for (int j = 0; j < 8; ++j) {
        float dx = __fsub_rn(px[j], cx);
        float dy = __fsub_rn(py[j], cy);
        float dz = __fsub_rn(pz[j], cz);
        float d2 = __fadd_rn(__fadd_rn(__fmul_rn(dx,dx), __fmul_rn(dy,dy)), __fmul_rn(dz,dz));
        mind[j] = fminf(mind[j], d2);
        u64 key = ((u64)__float_as_uint(mind[j]) << 32) | noi[j];
        kk = key > kk ? key : kk;
      }
      DPP64_MAX_ALL(kk);             // result lane 63
      wk_lo = (u32)__builtin_amdgcn_readlane((int)(u32)kk, 63);
      wk_hi = (u32)__builtin_amdgcn_readlane((int)(u32)(kk >> 32), 63);
    }
    if (lane == 0) wmax[pr][w] = ((u64)wk_hi << 32) | wk_lo;
    __syncthreads();   // single barrier per step (parity double-buffer)
    u64 w0 = wmax[pr][0], w1 = wmax[pr][1], w2 = wmax[pr][2], w3 = wmax[pr][3];
    u64 w4 = wmax[pr][4], w5 = wmax[pr][5], w6 = wmax[pr][6], w7 = wmax[pr][7];
    u64 a0 = w0 > w1 ? w0 : w1;
    u64 a1 = w2 > w3 ? w2 : w3;
    u64 a2 = w4 > w5 ? w4 : w5;
    u64 a3 = w6 > w7 ? w6 : w7;
    a0 = a0 > a1 ? a0 : a1;
    a2 = a2 > a3 ? a2 : a3;
    u64 W = a0 > a2 ? a0 : a2;
    last = (int)(~(u32)W);
    if (t == 0) {
      idx_out[b*MPC + m] = last;
      size_t po = ((size_t)b*MPC + m)*3;
      pos_out[po+0] = sx[last]; pos_out[po+1] = sy[last]; pos_out[po+2] = sz[last];
    }
  }
}

// ---------------------------------------------------------------- y = x @ W1[:64]  (f32 accum, bf16 store)
__global__ __launch_bounds__(256)
void y_kernel(const float* __restrict__ x, const float* __restrict__ w1,
              u16* __restrict__ y) {
  __shared__ float xs[64][68];
  __shared__ float ws[64][68];
  const int t = threadIdx.x;
  const size_t row0 = (size_t)blockIdx.x * 64;
#pragma unroll
  for (int k = 0; k < 4; ++k) {
    int l = t + 256*k;               // 0..1023 float4 index
    int r = l >> 4, c4 = l & 15;
    *(float4*)&xs[r][c4*4] = *(const float4*)&x[(row0 + r)*64 + c4*4];
    *(float4*)&ws[r][c4*4] = *(const float4*)&w1[r*64 + c4*4];
  }
  __syncthreads();
  const int r = t >> 2, c0 = (t & 3) << 4;
  float acc[16];
#pragma unroll
  for (int i = 0; i < 16; ++i) acc[i] = 0.f;
  for (int k = 0; k < 64; ++k) {
    float a = xs[r][k];
#pragma unroll
    for (int j = 0; j < 4; ++j) {
      float4 wv = *(const float4*)&ws[k][c0 + 4*j];
      acc[4*j+0] += a * wv.x; acc[4*j+1] += a * wv.y;
      acc[4*j+2] += a * wv.z; acc[4*j+3] += a * wv.w;
    }
  }
  u32 u[8];
#pragma unroll
  for (int i = 0; i < 8; ++i)
    u[i] = (u32)f2bf(acc[2*i]) | ((u32)f2bf(acc[2*i+1]) << 16);
  u16* dst = y + ((row0 + r)*64 + c0);
  ((uint4*)dst)[0] = make_uint4(u[0],u[1],u[2],u[3]);
  ((uint4*)dst)[1] = make_uint4(u[4],u[5],u[6],u[7]);
}

// ---------------------------------------------------------------- W2 -> bf16 transposed [128][64]
__global__ __launch_bounds__(256)
void w2t_kernel(const float* __restrict__ w2, u16* __restrict__ w2t) {
  int t = blockIdx.x*256 + threadIdx.x;
  if (t < 64*128) {
    int k = t >> 7, c = t & 127;
    w2t[c*64 + k] = f2bf(w2[t]);
  }
}

// ---------------------------------------------------------------- radius + top-64 neighbors
// Replicates lax.top_k(-d2,64) stability via key=(d2_bits, idx) ranking.
__global__ __launch_bounds__(256)
void nbr_kernel(const float* __restrict__ pos, const int* __restrict__ idx,
                int* __restrict__ nbr, int* __restrict__ nvalid) {
  const int bid = blockIdx.x;
  const int sw = (bid & 7) * 512 + (bid >> 3);   // bijective XCD swizzle (4096 = 8*512)
  const int cloud = sw >> 8;
  const int mbase = (sw & 255) << 2;
  __shared__ float sx[NPC], sy[NPC], sz[NPC];
  __shared__ u64 cand[4][CAP];
  const float* P = pos + (size_t)cloud * NPC * 3;
  const int t = threadIdx.x;
  for (int i = t; i < NPC; i += 256) { sx[i]=P[3*i]; sy[i]=P[3*i+1]; sz[i]=P[3*i+2]; }
  __syncthreads();
  const int wv = t >> 6, lane = t & 63;
  const int m = mbase + wv;
  const int g = cloud * MPC + m;
  const int ci = idx[g];
  const float cx = sx[ci], cy = sy[ci], cz = sz[ci];
  const float R2 = 0.04000000059604644775f;      // (float)(0.2*0.2)
  const u64 ltmask = (lane == 0) ? 0ull : (~0ull >> (64 - lane));
  int base = 0;
  for (int i = 0; i < NPC/64; ++i) {
    int j = (i << 6) + lane;
    float dx = __fsub_rn(cx, sx[j]);
    float dy = __fsub_rn(cy, sy[j]);
    float dz = __fsub_rn(cz, sz[j]);
    float d2 = __fadd_rn(__fadd_rn(__fmul_rn(dx,dx), __fmul_rn(dy,dy)), __fmul_rn(dz,dz));
    bool in = d2 <= R2;
    u64 mk = __ballot(in);
    if (in) {
      int slot = base + (int)__popcll(mk & ltmask);
      if (slot < CAP)
        cand[wv][slot] = ((u64)__float_as_uint(d2) << 32) | (u32)j;
    }
    base += (int)__popcll(mk);
  }
  int cnt = base < CAP ? base : CAP;
  u64 mykey[7];
  int myrank[7];
#pragma unroll
  for (int u = 0; u < 7; ++u) {
    int s = lane + (u << 6);
    mykey[u] = (s < cnt) ? cand[wv][s] : ~0ull;
    myrank[u] = 0;
  }
  for (int jj = 0; jj < cnt; ++jj) {
    u64 kj = cand[wv][jj];
#pragma unroll
    for (int u = 0; u < 7; ++u) myrank[u] += (kj < mykey[u]) ? 1 : 0;
  }
#pragma unroll
  for (int u = 0; u < 7; ++u) {
    int s = lane + (u << 6);
    if (s < cnt && myrank[u] < KNB)
      nbr[(size_t)g*KNB + myrank[u]] = cloud*NPC + (int)(mykey[u] & 0xffffffffull);
  }
  if (lane == 0) nvalid[g] = cnt < KNB ? cnt : KNB;
}

// ---------------------------------------------------------------- PointNetConv (one block per centroid)
__global__ __launch_bounds__(256)
void conv_kernel(const float* __restrict__ pos, const int* __restrict__ idx,
                 const int* __restrict__ nbr, const int* __restrict__ nvalid,
                 const u16* __restrict__ y, const u16* __restrict__ w2t,
                 const float* __restrict__ w1, const float* __restrict__ b1,
                 const float* __restrict__ b2, float* __restrict__ out) {
  const int bid = blockIdx.x;
  const int g = (bid & 7) * 2048 + (bid >> 3);   // bijective XCD swizzle (16384 = 8*2048)
  const int cloud = g >> 10;
  __shared__ u16 YH[64][72];     // y rows, then relu'd H1 in-place (same-thread RMW)
  __shared__ u16 WT[128][72];    // W2^T bf16
  __shared__ float rel[64][3];
  __shared__ int nbs[64];
  __shared__ float w1p[192];
  __shared__ float b1s[64];
  const int t = threadIdx.x;
  const int nv = nvalid[g];
  if (t < 64) nbs[t] = (t < nv) ? nbr[(size_t)g*KNB + t] : -1;
  if (t < 192) w1p[t] = w1[64*64 + t];
  else         b1s[t - 192] = b1[t - 192];
  __syncthreads();
  if (t < 64) {
    int ci = cloud*NPC + idx[g];
    float cxx = pos[3*ci], cyy = pos[3*ci+1], czz = pos[3*ci+2];
    int j = nbs[t];
    float r0 = 0.f, r1 = 0.f, r2 = 0.f;
    if (t < nv && j >= 0) {
      r0 = pos[3*j]   - cxx;
      r1 = pos[3*j+1] - cyy;
      r2 = pos[3*j+2] - czz;
    }
    rel[t][0] = r0; rel[t][1] = r1; rel[t][2] = r2;
  }
  {
    int row = t >> 2, part = t & 3;
    int j = nbs[row];
    uint4 v0 = make_uint4(0,0,0,0), v1 = make_uint4(0,0,0,0);
    if (row < nv && j >= 0) {
      const uint4* src = (const uint4*)(y + (size_t)j*64);
      v0 = src[part*2]; v1 = src[part*2 + 1];
    }
    *(uint4*)&YH[row][part*16]     = v0;
    *(uint4*)&YH[row][part*16 + 8] = v1;
  }
#pragma unroll
  for (int k = 0; k < 4; ++k) {
    int l = t + 256*k;             // 1024 uint4 total
    int row = l >> 3, part = l & 7;
    *(uint4*)&WT[row][part*8] = ((const uint4*)w2t)[l];
  }
  __syncthreads();
  {
    int s = t >> 2, c0 = (t & 3) << 4;
    float rx = rel[s][0], ry = rel[s][1], rz = rel[s][2];
#pragma unroll
    for (int c = 0; c < 16; ++c) {
      int cc = c0 + c;
      float v = bf2f(YH[s][cc]) + rx*w1p[cc] + ry*w1p[64+cc] + rz*w1p[128+cc] + b1s[cc];
      v = fmaxf(v, 0.f);
      YH[s][cc] = f2bf(v);
    }
  }
  __syncthreads();
  const int wv = t >> 6, lane = t & 63;
  const int arow = lane & 15, agrp = lane >> 4;
  const int col0 = wv << 5;
  f32x4 acc[4][2];
#pragma unroll
  for (int mt = 0; mt < 4; ++mt)
#pragma unroll
    for (int nt = 0; nt < 2; ++nt) {
      f32x4 z = {0.f, 0.f, 0.f, 0.f};
      acc[mt][nt] = z;
    }
#pragma unroll
  for (int kk = 0; kk < 2; ++kk) {
    short8 a[4], bm[2];
#pragma unroll
    for (int mt = 0; mt < 4; ++mt)
      a[mt] = *(const short8*)&YH[mt*16 + arow][kk*32 + agrp*8];
#pragma unroll
    for (int nt = 0; nt < 2; ++nt)
      bm[nt] = *(const short8*)&WT[col0 + nt*16 + arow][kk*32 + agrp*8];
#pragma unroll
    for (int mt = 0; mt < 4; ++mt)
#pragma unroll
      for (int nt = 0; nt < 2; ++nt)
        acc[mt][nt] = __builtin_amdgcn_mfma_f32_16x16x32_bf16(a[mt], bm[nt], acc[mt][nt], 0, 0, 0);
  }
  float p0 = -__builtin_inff(), p1 = -__builtin_inff();
#pragma unroll
  for (int mt = 0; mt < 4; ++mt) {
#pragma unroll
    for (int r = 0; r < 4; ++r) {
      int slot = mt*16 + agrp*4 + r;
      if (slot < nv) {
        p0 = fmaxf(p0, acc[mt][0][r]);
        p1 = fmaxf(p1, acc[mt][1][r]);
      }
    }
  }
  p0 = fmaxf(p0, __shfl_xor(p0, 16, 64));
  p0 = fmaxf(p0, __shfl_xor(p0, 32, 64));
  p1 = fmaxf(p1, __shfl_xor(p1, 16, 64));
  p1 = fmaxf(p1, __shfl_xor(p1, 32, 64));
  if (lane < 16) {
    int c = col0 + lane;
    out[(size_t)g*128 + c]      = (nv > 0) ? p0 + b2[c]      : 0.f;
    out[(size_t)g*128 + c + 16] = (nv > 0) ? p1 + b2[c + 16] : 0.f;
  }
}

// ---------------------------------------------------------------- launch
extern "C" void kernel_launch(void* const* d_in, const int* in_sizes, int n_in,
                              void* d_out, int out_size, void* d_ws, size_t ws_size,
                              hipStream_t stream) {
  const float* x   = (const float*)d_in[0];
  const float* pos = (const float*)d_in[1];
  // d_in[2] (batch) unused: layout is known (repeat arange(16), 4096 each)
  const float* W1  = (const float*)d_in[3];
  const float* b1  = (const float*)d_in[4];
  const float* W2  = (const float*)d_in[5];
  const float* b2  = (const float*)d_in[6];

  float* out       = (float*)d_out;                    // [16384,128]
  float* pos_out   = out + (size_t)NB*MPC*128;         // [16384,3]
  float* batch_out = pos_out + (size_t)NB*MPC*3;       // [16384] (written as floats)

  char* ws = (char*)d_ws;
  int* idx    = (int*)(ws);                                    // 16384 * 4   = 64 KB
  int* nvalid = (int*)(ws + 65536);                            // 16384 * 4   = 64 KB
  int* nbr    = (int*)(ws + 131072);                           // 16384*64*4  = 4 MB
  u16* w2t    = (u16*)(ws + 131072 + 4194304);                 // 128*64*2    = 16 KB
  u16* y      = (u16*)(ws + 131072 + 4194304 + 16384);         // 65536*64*2  = 8 MB (16B aligned)

  fps_kernel <<<NB,    512,  0, stream>>>(pos, idx, pos_out, batch_out);
  y_kernel   <<<1024,  256,  0, stream>>>(x, W1, y);
  w2t_kernel <<<32,    256,  0, stream>>>(W2, w2t);
  nbr_kernel <<<4096,  256,  0, stream>>>(pos, idx, nbr, nvalid);
  conv_kernel<<<16384, 256,  0, stream>>>(pos, idx, nbr, nvalid, y, w2t, W1, b1, b2, out);
}